// Round 17
// baseline (54.943 us; speedup 1.0000x reference)
//
#include <hip/hip_runtime.h>

typedef __attribute__((ext_vector_type(4))) float f32x4;
typedef __attribute__((ext_vector_type(8))) short short8;
typedef __attribute__((ext_vector_type(8))) __bf16 bf16x8;

constexpr int kN = 4096;
constexpr int kF = 256;
constexpr int kH = 4;
constexpr int kD = 64;
constexpr int kMP = 264;  // lmask c-stride (bytes), padded to break bank aliasing
constexpr float kLog2e = 1.4426950408889634f;

__device__ __forceinline__ unsigned short f2us(float x) {
  __bf16 b = (__bf16)x;
  return __builtin_bit_cast(unsigned short, b);
}

// ---------------------------------------------------------------------------
// k_wh (fused wswz): stages W[h] -> LDS bf16 B-frags, Wh = h @ W[h] via MFMA,
// writes whb (pre-swizzled B-frag order) + s_src/s_dst + per-block pmax.
// ---------------------------------------------------------------------------
__global__ __launch_bounds__(256) void k_wh(const float* __restrict__ hmat,
                                            const float* __restrict__ W,
                                            const float* __restrict__ a_src,
                                            const float* __restrict__ a_dst,
                                            unsigned short* __restrict__ whb,
                                            float* __restrict__ s_src,
                                            float* __restrict__ s_dst,
                                            float* __restrict__ pmax) {
  const int h = blockIdx.x & 3, rb = blockIdx.x >> 2;
  const int row0 = rb * 64;
  const int t = threadIdx.x;
  __shared__ unsigned short wlds[16384];
  __shared__ float bm[4];
  {
    const int d = t & 63;
    const int dt = d >> 4, dl = d & 15;
    for (int kb = 0; kb < 64; kb++) {
      const int k = kb * 4 + (t >> 6);
      const float wv = W[((size_t)h * kF + k) * kD + d];
      const int ks = k >> 5, kl = k & 31;
      const int lane2 = ((kl >> 3) << 4) | dl;
      const int e = kl & 7;
      wlds[(((ks * 4 + dt) * 64 + lane2) << 3) + e] = f2us(wv);
    }
  }
  __syncthreads();
  const int wave = t >> 6, lane = t & 63;
  const int lr = lane & 15, lg = lane >> 4;
  const int nrow = row0 + wave * 16 + lr;
  f32x4 acc[4] = {};
  const float* hrow = hmat + (size_t)nrow * kF + 8 * lg;
#pragma unroll
  for (int ks = 0; ks < 8; ks++) {
    const f32x4 h0 = *reinterpret_cast<const f32x4*>(hrow + ks * 32);
    const f32x4 h1 = *reinterpret_cast<const f32x4*>(hrow + ks * 32 + 4);
    bf16x8 af;
#pragma unroll
    for (int j = 0; j < 4; j++) { af[j] = (__bf16)h0[j]; af[4 + j] = (__bf16)h1[j]; }
#pragma unroll
    for (int dt = 0; dt < 4; dt++) {
      const short8 bs = *reinterpret_cast<const short8*>(wlds + (((ks * 4 + dt) * 64 + lane) << 3));
      acc[dt] = __builtin_amdgcn_mfma_f32_16x16x32_bf16(af, __builtin_bit_cast(bf16x8, bs), acc[dt], 0, 0, 0);
    }
  }
#pragma unroll
  for (int dt = 0; dt < 4; dt++) {
#pragma unroll
    for (int r = 0; r < 4; r++) {
      const int n = row0 + wave * 16 + lg * 4 + r;
      const int mstep = n >> 5, kl = n & 31;
      const int lane2 = ((kl >> 3) << 4) | lr;
      const int e = kl & 7;
      whb[((((size_t)(h * 128 + mstep) * 4 + dt) * 64 + lane2) << 3) + e] = f2us(acc[dt][r]);
    }
  }
  float as4[4], ad4[4];
#pragma unroll
  for (int dt = 0; dt < 4; dt++) {
    as4[dt] = a_src[h * kD + dt * 16 + lr];
    ad4[dt] = a_dst[h * kD + dt * 16 + lr];
  }
  float wmax = -1e30f;
#pragma unroll
  for (int r = 0; r < 4; r++) {
    float ps = acc[0][r] * as4[0] + acc[1][r] * as4[1] + acc[2][r] * as4[2] + acc[3][r] * as4[3];
    float pd = acc[0][r] * ad4[0] + acc[1][r] * ad4[1] + acc[2][r] * ad4[2] + acc[3][r] * ad4[3];
#pragma unroll
    for (int off = 1; off < 16; off <<= 1) {
      ps += __shfl_xor(ps, off);
      pd += __shfl_xor(pd, off);
    }
    const int n = row0 + wave * 16 + lg * 4 + r;
    if (lr == 0) { s_src[h * kN + n] = ps; s_dst[h * kN + n] = pd; }
    wmax = fmaxf(wmax, pd);
  }
  wmax = fmaxf(wmax, __shfl_xor(wmax, 16));
  wmax = fmaxf(wmax, __shfl_xor(wmax, 32));
  if (lane == 0) bm[wave] = wmax;
  __syncthreads();
  if (t == 0)
    pmax[blockIdx.x] = fmaxf(fmaxf(bm[0], bm[1]), fmaxf(bm[2], bm[3]));
}

// masked value via sign-extended bit AND
__device__ __forceinline__ float msel(float pv, unsigned m, int j) {
  const unsigned keep = (unsigned)(-(int)((m >> j) & 1u));
  return __builtin_bit_cast(float, __builtin_bit_cast(unsigned, pv) & keep);
}

// p = mask * max(E1*K1, E2*K2)
__device__ __forceinline__ bf16x8 make_p2(const f32x4 E1a, const f32x4 E1b,
                                          const f32x4 E2a, const f32x4 E2b,
                                          const float K1, const float K2,
                                          const unsigned int m) {
  bf16x8 r;
#pragma unroll
  for (int j = 0; j < 4; j++)
    r[j] = (__bf16)msel(fmaxf(E1a[j] * K1, E2a[j] * K2), m, j);
#pragma unroll
  for (int j = 0; j < 4; j++)
    r[4 + j] = (__bf16)msel(fmaxf(E1b[j] * K1, E2b[j] * K2), m, 4 + j);
  return r;
}

// ---------------------------------------------------------------------------
// k_attn: 1024 blocks = 128 rowgroups(32 rows) x 8 col-splits(512 cols).
// 512 threads = 8 waves = 4 heads x 2 q. 4 blocks/CU -> 8 waves/SIMD while
// KEEPING the 2-row-tile B-frag amortization (B traffic unchanged 256 MB).
// Per wave: 8 units x 2 row-tiles; per-wave serial chain halves vs round 15.
// Epilogue: two sequential LDS combine passes (acc0, then acc1).
// ---------------------------------------------------------------------------
__global__ __launch_bounds__(512, 4) void k_attn(const float* __restrict__ adj,
                                                 const unsigned short* __restrict__ whb,
                                                 const float* __restrict__ s_src,
                                                 const float* __restrict__ s_dst,
                                                 const float* __restrict__ pmax,
                                                 float* __restrict__ accP,
                                                 float* __restrict__ zP) {
  const int bid = blockIdx.x;
  const int rb = bid >> 3, cs = bid & 7;
  const int row0 = rb * 32;
  const int colbase = cs * 512;
  const int t = threadIdx.x;
  const int wave = t >> 6, lane = t & 63;
  const int h = wave & 3, q = wave >> 2;
  const int lr = lane & 15, lg = lane >> 4;

  __shared__ float el1[4][512];              // 8 KB (E1; combine half A)
  __shared__ float el2[4][512];              // 8 KB (E2; combine half B)
  __shared__ unsigned char lmaskB[8 * kMP];  // 2.1 KB
  __shared__ float zx[4][32];

  // ---- Phase 1: adj tile (32 x 512) -> mask bytes (batched, VALU pack) ----
  {
    f32x4 v[8];
    const float* abase = adj + (size_t)(row0 + wave * 4) * kN + colbase + 8 * lane;
#pragma unroll
    for (int j = 0; j < 4; j++)
#pragma unroll
      for (int p = 0; p < 2; p++)
        v[j * 2 + p] = *reinterpret_cast<const f32x4*>(abase + (size_t)j * kN + 4 * p);
#pragma unroll
    for (int j = 0; j < 4; j++) {
      const int rl = wave * 4 + j;
      unsigned int b = 0;
#pragma unroll
      for (int i = 0; i < 4; i++) {
        b |= (v[j * 2][i] != 0.0f ? 1u : 0u) << i;
        b |= (v[j * 2 + 1][i] != 0.0f ? 1u : 0u) << (4 + i);
      }
      // octet o = lane (cols 8*lane..8*lane+8); c = lane>>3, s = lane&7
      lmaskB[(lane >> 3) * kMP + rl * 8 + (lane & 7)] = (unsigned char)b;
    }
  }

  // ---- E-tables: 512 f32x4 slots over 512 threads ----
  {
    const int hh = t >> 7, c4 = (t & 127) * 4;
    const f32x4 sd = *reinterpret_cast<const f32x4*>(s_dst + hh * kN + colbase + c4);
    f32x4 e1, e2;
#pragma unroll
    for (int i = 0; i < 4; i++) {
      const float u = sd[i] * kLog2e;
      e1[i] = __builtin_amdgcn_exp2f(u);
      e2[i] = __builtin_amdgcn_exp2f(0.2f * u);
    }
    *reinterpret_cast<f32x4*>(&el1[hh][c4]) = e1;
    *reinterpret_cast<f32x4*>(&el2[hh][c4]) = e2;
  }

  // ---- M = exact global max of s_dst[h] via pmax[64 blocks] + shfl ----
  float M = pmax[(lane << 2) | h];
#pragma unroll
  for (int off = 1; off < 64; off <<= 1) M = fmaxf(M, __shfl_xor(M, off));

  float K1[2], K2[2];
#pragma unroll
  for (int rt = 0; rt < 2; rt++) {
    const float A = s_src[h * kN + row0 + rt * 16 + lr];
    const float xb = A + M;
    const float B = fmaxf(xb, 0.2f * xb);
    K1[rt] = __builtin_amdgcn_exp2f((A - B) * kLog2e);
    K2[rt] = __builtin_amdgcn_exp2f((0.2f * A - B) * kLog2e);
  }

  __syncthreads();

  // ---- mask preload: 8 bytes per row-tile per lane (unit u = chunk u) ----
  const int Boff = (q << 2) | lg;
  unsigned int cw0[2], cw1[2];
#pragma unroll
  for (int w = 0; w < 2; w++) {
    unsigned int a0 = 0, a1 = 0;
#pragma unroll
    for (int d = 0; d < 4; d++) {
      const int c = w * 4 + d;
      a0 |= (unsigned int)lmaskB[c * kMP + lr * 8 + Boff] << (8 * d);
      a1 |= (unsigned int)lmaskB[c * kMP + (lr + 16) * 8 + Boff] << (8 * d);
    }
    cw0[w] = a0; cw1[w] = a1;
  }

  f32x4 acc0[4] = {}, acc1[4] = {};
  f32x4 accz0 = {}, accz1 = {};
  bf16x8 ones;
#pragma unroll
  for (int e = 0; e < 8; e++) ones[e] = (__bf16)1.0f;

  const float* e1p = &el1[h][q * 32 + 8 * lg];
  const float* e2p = &el2[h][q * 32 + 8 * lg];
  const short8* wb = reinterpret_cast<const short8*>(whb) + (size_t)h * 32768 + lane;
  const int mstep0 = cs * 16 + q;

  // 2-deep B-frag prefetch (overflow prefetches land in-ws, never consumed)
  short8 bw[2][4];
#pragma unroll
  for (int sx = 0; sx < 2; sx++) {
    const short8* p = wb + (size_t)(mstep0 + sx * 2) * 256;
    bw[sx][0] = p[0]; bw[sx][1] = p[64]; bw[sx][2] = p[128]; bw[sx][3] = p[192];
  }

  // 1-unit-ahead E-register prefetch
  f32x4 cE1a = *reinterpret_cast<const f32x4*>(e1p);
  f32x4 cE1b = *reinterpret_cast<const f32x4*>(e1p + 4);
  f32x4 cE2a = *reinterpret_cast<const f32x4*>(e2p);
  f32x4 cE2b = *reinterpret_cast<const f32x4*>(e2p + 4);

#pragma unroll
  for (int it = 0; it < 8; ++it) {
    const int nx = ((it + 1) & 7) * 64;
    const f32x4 nE1a = *reinterpret_cast<const f32x4*>(e1p + nx);
    const f32x4 nE1b = *reinterpret_cast<const f32x4*>(e1p + nx + 4);
    const f32x4 nE2a = *reinterpret_cast<const f32x4*>(e2p + nx);
    const f32x4 nE2b = *reinterpret_cast<const f32x4*>(e2p + nx + 4);

    const short8 cb0 = bw[it & 1][0], cb1 = bw[it & 1][1],
                 cb2 = bw[it & 1][2], cb3 = bw[it & 1][3];
    const short8* pp = wb + (size_t)(mstep0 + (it + 2) * 2) * 256;
    bw[it & 1][0] = pp[0];
    bw[it & 1][1] = pp[64];
    bw[it & 1][2] = pp[128];
    bw[it & 1][3] = pp[192];

    const unsigned cm0 = (cw0[it >> 2] >> ((it & 3) * 8)) & 0xFFu;
    const unsigned cm1 = (cw1[it >> 2] >> ((it & 3) * 8)) & 0xFFu;
    const bf16x8 P0 = make_p2(cE1a, cE1b, cE2a, cE2b, K1[0], K2[0], cm0);
    const bf16x8 P1 = make_p2(cE1a, cE1b, cE2a, cE2b, K1[1], K2[1], cm1);
    const bf16x8 B0 = __builtin_bit_cast(bf16x8, cb0);
    const bf16x8 B1 = __builtin_bit_cast(bf16x8, cb1);
    const bf16x8 B2 = __builtin_bit_cast(bf16x8, cb2);
    const bf16x8 B3 = __builtin_bit_cast(bf16x8, cb3);

    acc0[0] = __builtin_amdgcn_mfma_f32_16x16x32_bf16(P0, B0, acc0[0], 0, 0, 0);
    acc1[0] = __builtin_amdgcn_mfma_f32_16x16x32_bf16(P1, B0, acc1[0], 0, 0, 0);
    acc0[1] = __builtin_amdgcn_mfma_f32_16x16x32_bf16(P0, B1, acc0[1], 0, 0, 0);
    acc1[1] = __builtin_amdgcn_mfma_f32_16x16x32_bf16(P1, B1, acc1[1], 0, 0, 0);
    acc0[2] = __builtin_amdgcn_mfma_f32_16x16x32_bf16(P0, B2, acc0[2], 0, 0, 0);
    acc1[2] = __builtin_amdgcn_mfma_f32_16x16x32_bf16(P1, B2, acc1[2], 0, 0, 0);
    acc0[3] = __builtin_amdgcn_mfma_f32_16x16x32_bf16(P0, B3, acc0[3], 0, 0, 0);
    acc1[3] = __builtin_amdgcn_mfma_f32_16x16x32_bf16(P1, B3, acc1[3], 0, 0, 0);
    accz0 = __builtin_amdgcn_mfma_f32_16x16x32_bf16(P0, ones, accz0, 0, 0, 0);
    accz1 = __builtin_amdgcn_mfma_f32_16x16x32_bf16(P1, ones, accz1, 0, 0, 0);

    cE1a = nE1a; cE1b = nE1b; cE2a = nE2a; cE2b = nE2b;
  }

  // ---- q-combine: two sequential LDS passes (acc0 then acc1) ----
  const size_t ob = ((size_t)(cs * 4 + h) * kN + row0) * kD;
  __syncthreads();
  if (q == 1) {
    // acc0 dump: dt 0-1 -> el1[h], dt 2-3 -> el2[h]
#pragma unroll
    for (int dt = 0; dt < 2; dt++) {
      *reinterpret_cast<f32x4*>(&el1[h][(dt * 64 + lane) * 4]) = acc0[dt];
      *reinterpret_cast<f32x4*>(&el2[h][(dt * 64 + lane) * 4]) = acc0[dt + 2];
    }
    if (lr == 0) {
#pragma unroll
      for (int r = 0; r < 4; r++) {
        zx[h][lg * 4 + r] = accz0[r];
        zx[h][16 + lg * 4 + r] = accz1[r];
      }
    }
  }
  __syncthreads();
  if (q == 0) {
#pragma unroll
    for (int dt = 0; dt < 2; dt++) {
      acc0[dt] += *reinterpret_cast<const f32x4*>(&el1[h][(dt * 64 + lane) * 4]);
      acc0[dt + 2] += *reinterpret_cast<const f32x4*>(&el2[h][(dt * 64 + lane) * 4]);
    }
#pragma unroll
    for (int dt = 0; dt < 4; dt++)
#pragma unroll
      for (int r = 0; r < 4; r++)
        accP[ob + (size_t)(lg * 4 + r) * kD + dt * 16 + lr] = acc0[dt][r];
  }
  __syncthreads();
  if (q == 1) {
    // acc1 dump
#pragma unroll
    for (int dt = 0; dt < 2; dt++) {
      *reinterpret_cast<f32x4*>(&el1[h][(dt * 64 + lane) * 4]) = acc1[dt];
      *reinterpret_cast<f32x4*>(&el2[h][(dt * 64 + lane) * 4]) = acc1[dt + 2];
    }
  }
  __syncthreads();
  if (q == 0) {
#pragma unroll
    for (int dt = 0; dt < 2; dt++) {
      acc1[dt] += *reinterpret_cast<const f32x4*>(&el1[h][(dt * 64 + lane) * 4]);
      acc1[dt + 2] += *reinterpret_cast<const f32x4*>(&el2[h][(dt * 64 + lane) * 4]);
    }
#pragma unroll
    for (int dt = 0; dt < 4; dt++)
#pragma unroll
      for (int r = 0; r < 4; r++)
        accP[ob + (size_t)(16 + lg * 4 + r) * kD + dt * 16 + lr] = acc1[dt][r];
    if (lr == 0) {
      const size_t zb = (size_t)(cs * 4 + h) * kN + row0;
#pragma unroll
      for (int r = 0; r < 4; r++) {
        zP[zb + lg * 4 + r] = accz0[r] + zx[h][lg * 4 + r];
        zP[zb + 16 + lg * 4 + r] = accz1[r] + zx[h][16 + lg * 4 + r];
      }
    }
  }
}

// ---------------------------------------------------------------------------
// k_fin: out[n][h*64+d] = elu( sum_cs acc / sum_cs z ), 8 col-splits
// ---------------------------------------------------------------------------
__global__ __launch_bounds__(256) void k_fin(const float* __restrict__ accP,
                                             const float* __restrict__ zP,
                                             float* __restrict__ out) {
  const int idx = blockIdx.x * 256 + threadIdx.x;  // 262144 float4s
  const int d4 = idx & 15;
  const int hh = (idx >> 4) & 3;
  const int n = idx >> 6;
  f32x4 v = {};
  float z = 0.0f;
#pragma unroll
  for (int s = 0; s < 8; s++) {
    v += reinterpret_cast<const f32x4*>(accP)[((size_t)(s * 4 + hh) * kN + n) * 16 + d4];
    z += zP[(size_t)(s * 4 + hh) * kN + n];
  }
  const float rz = 1.0f / z;
  f32x4 o;
#pragma unroll
  for (int j = 0; j < 4; j++) {
    const float x = v[j] * rz;
    o[j] = x > 0.0f ? x : (__builtin_amdgcn_exp2f(x * kLog2e) - 1.0f);
  }
  reinterpret_cast<f32x4*>(out)[(size_t)n * 64 + hh * 16 + d4] = o;
}

extern "C" void kernel_launch(void* const* d_in, const int* in_sizes, int n_in,
                              void* d_out, int out_size, void* d_ws, size_t ws_size,
                              hipStream_t stream) {
  const float* hmat  = (const float*)d_in[0];
  const float* adj   = (const float*)d_in[1];
  const float* W     = (const float*)d_in[2];
  const float* a_src = (const float*)d_in[3];
  const float* a_dst = (const float*)d_in[4];
  float* out = (float*)d_out;

  char* ws = (char*)d_ws;
  unsigned short* whb = (unsigned short*)(ws);       // 2 MB    @0
  float* s_src  = (float*)(ws + 0x200000);           // 64 KB
  float* s_dst  = (float*)(ws + 0x210000);           // 64 KB
  float* pmax   = (float*)(ws + 0x220000);           // 1 KB
  float* accP   = (float*)(ws + 0x240000);           // 32 MB (8 col-splits)
  float* zP     = (float*)(ws + 0x2240000);          // 512 KB

  hipLaunchKernelGGL(k_wh, dim3(256), dim3(256), 0, stream,
                     hmat, W, a_src, a_dst, whb, s_src, s_dst, pmax);
  hipLaunchKernelGGL(k_attn, dim3(1024), dim3(512), 0, stream,
                     adj, whb, s_src, s_dst, pmax, accP, zP);
  hipLaunchKernelGGL(k_fin, dim3(1024), dim3(256), 0, stream, accP, zP, out);
}

// Round 18
// 51.268 us; speedup vs baseline: 1.0717x; 1.0717x over previous
//
#include <hip/hip_runtime.h>

typedef __attribute__((ext_vector_type(4))) float f32x4;
typedef __attribute__((ext_vector_type(8))) short short8;
typedef __attribute__((ext_vector_type(8))) __bf16 bf16x8;

constexpr int kN = 4096;
constexpr int kF = 256;
constexpr int kH = 4;
constexpr int kD = 64;
constexpr int kMP = 264;  // lmask c-stride (bytes), padded to break bank aliasing
constexpr float kLog2e = 1.4426950408889634f;

__device__ __forceinline__ unsigned short f2us(float x) {
  __bf16 b = (__bf16)x;
  return __builtin_bit_cast(unsigned short, b);
}

// ---------------------------------------------------------------------------
// k_wh (fused wswz): stages W[h] -> LDS bf16 B-frags, Wh = h @ W[h] via MFMA,
// writes whb (pre-swizzled B-frag order) + s_src/s_dst + per-block pmax.
// ---------------------------------------------------------------------------
__global__ __launch_bounds__(256) void k_wh(const float* __restrict__ hmat,
                                            const float* __restrict__ W,
                                            const float* __restrict__ a_src,
                                            const float* __restrict__ a_dst,
                                            unsigned short* __restrict__ whb,
                                            float* __restrict__ s_src,
                                            float* __restrict__ s_dst,
                                            float* __restrict__ pmax) {
  const int h = blockIdx.x & 3, rb = blockIdx.x >> 2;
  const int row0 = rb * 64;
  const int t = threadIdx.x;
  __shared__ unsigned short wlds[16384];
  __shared__ float bm[4];
  {
    const int d = t & 63;
    const int dt = d >> 4, dl = d & 15;
    for (int kb = 0; kb < 64; kb++) {
      const int k = kb * 4 + (t >> 6);
      const float wv = W[((size_t)h * kF + k) * kD + d];
      const int ks = k >> 5, kl = k & 31;
      const int lane2 = ((kl >> 3) << 4) | dl;
      const int e = kl & 7;
      wlds[(((ks * 4 + dt) * 64 + lane2) << 3) + e] = f2us(wv);
    }
  }
  __syncthreads();
  const int wave = t >> 6, lane = t & 63;
  const int lr = lane & 15, lg = lane >> 4;
  const int nrow = row0 + wave * 16 + lr;
  f32x4 acc[4] = {};
  const float* hrow = hmat + (size_t)nrow * kF + 8 * lg;
#pragma unroll
  for (int ks = 0; ks < 8; ks++) {
    const f32x4 h0 = *reinterpret_cast<const f32x4*>(hrow + ks * 32);
    const f32x4 h1 = *reinterpret_cast<const f32x4*>(hrow + ks * 32 + 4);
    bf16x8 af;
#pragma unroll
    for (int j = 0; j < 4; j++) { af[j] = (__bf16)h0[j]; af[4 + j] = (__bf16)h1[j]; }
#pragma unroll
    for (int dt = 0; dt < 4; dt++) {
      const short8 bs = *reinterpret_cast<const short8*>(wlds + (((ks * 4 + dt) * 64 + lane) << 3));
      acc[dt] = __builtin_amdgcn_mfma_f32_16x16x32_bf16(af, __builtin_bit_cast(bf16x8, bs), acc[dt], 0, 0, 0);
    }
  }
#pragma unroll
  for (int dt = 0; dt < 4; dt++) {
#pragma unroll
    for (int r = 0; r < 4; r++) {
      const int n = row0 + wave * 16 + lg * 4 + r;
      const int mstep = n >> 5, kl = n & 31;
      const int lane2 = ((kl >> 3) << 4) | lr;
      const int e = kl & 7;
      whb[((((size_t)(h * 128 + mstep) * 4 + dt) * 64 + lane2) << 3) + e] = f2us(acc[dt][r]);
    }
  }
  float as4[4], ad4[4];
#pragma unroll
  for (int dt = 0; dt < 4; dt++) {
    as4[dt] = a_src[h * kD + dt * 16 + lr];
    ad4[dt] = a_dst[h * kD + dt * 16 + lr];
  }
  float wmax = -1e30f;
#pragma unroll
  for (int r = 0; r < 4; r++) {
    float ps = acc[0][r] * as4[0] + acc[1][r] * as4[1] + acc[2][r] * as4[2] + acc[3][r] * as4[3];
    float pd = acc[0][r] * ad4[0] + acc[1][r] * ad4[1] + acc[2][r] * ad4[2] + acc[3][r] * ad4[3];
#pragma unroll
    for (int off = 1; off < 16; off <<= 1) {
      ps += __shfl_xor(ps, off);
      pd += __shfl_xor(pd, off);
    }
    const int n = row0 + wave * 16 + lg * 4 + r;
    if (lr == 0) { s_src[h * kN + n] = ps; s_dst[h * kN + n] = pd; }
    wmax = fmaxf(wmax, pd);
  }
  wmax = fmaxf(wmax, __shfl_xor(wmax, 16));
  wmax = fmaxf(wmax, __shfl_xor(wmax, 32));
  if (lane == 0) bm[wave] = wmax;
  __syncthreads();
  if (t == 0)
    pmax[blockIdx.x] = fmaxf(fmaxf(bm[0], bm[1]), fmaxf(bm[2], bm[3]));
}

// masked value via sign-extended bit AND (proven in rounds 12/13/15/16)
__device__ __forceinline__ float msel(float pv, unsigned m, int j) {
  const unsigned keep = (unsigned)(-(int)((m >> j) & 1u));
  return __builtin_bit_cast(float, __builtin_bit_cast(unsigned, pv) & keep);
}

// p = mask * max(E1*K1, E2*K2)
__device__ __forceinline__ bf16x8 make_p2(const f32x4 E1a, const f32x4 E1b,
                                          const f32x4 E2a, const f32x4 E2b,
                                          const float K1, const float K2,
                                          const unsigned int m) {
  bf16x8 r;
#pragma unroll
  for (int j = 0; j < 4; j++)
    r[j] = (__bf16)msel(fmaxf(E1a[j] * K1, E2a[j] * K2), m, j);
#pragma unroll
  for (int j = 0; j < 4; j++)
    r[4 + j] = (__bf16)msel(fmaxf(E1b[j] * K1, E2b[j] * K2), m, 4 + j);
  return r;
}

// ---------------------------------------------------------------------------
// k_attn (fused abits, pipelined): 512 blocks = 128 rowgroups(32) x 4
// col-splits(1024). 8 waves = 4 heads x 2 col-interleaves. Phase 1: lane-
// batched adj loads -> VALU mask-byte pack -> padded LDS. Phase 2: 16 units
// x 2 row-tiles per wave, 2-deep B prefetch, hoisted exp2, 1-unit-ahead
// E-table register prefetch. BEST-KNOWN CONFIG (51.3 us total).
// ---------------------------------------------------------------------------
__global__ __launch_bounds__(512, 4) void k_attn(const float* __restrict__ adj,
                                                 const unsigned short* __restrict__ whb,
                                                 const float* __restrict__ s_src,
                                                 const float* __restrict__ s_dst,
                                                 const float* __restrict__ pmax,
                                                 float* __restrict__ accP,
                                                 float* __restrict__ zP) {
  const int bid = blockIdx.x;
  const int rb = bid >> 2, cs = bid & 3;
  const int row0 = rb * 32;
  const int colbase = cs * 1024;
  const int t = threadIdx.x;
  const int wave = t >> 6, lane = t & 63;
  const int h = wave & 3, q = wave >> 2;
  const int lr = lane & 15, lg = lane >> 4;

  __shared__ float el1[4][1024];
  __shared__ float el2[4][1024];
  __shared__ unsigned char lmaskB[16 * kMP];
  __shared__ float zx[4][32];

  // ---- Phase 1: adj tile -> mask bytes (batched loads, VALU-only pack) ----
  {
    f32x4 v[16];
    const float* abase = adj + (size_t)(row0 + wave * 4) * kN + colbase;
#pragma unroll
    for (int j = 0; j < 4; j++)
#pragma unroll
      for (int p = 0; p < 4; p++) {
        const int off = ((p >> 1) << 9) + 8 * lane + ((p & 1) << 2);
        v[j * 4 + p] = *reinterpret_cast<const f32x4*>(abase + (size_t)j * kN + off);
      }
#pragma unroll
    for (int j = 0; j < 4; j++) {
      const int rl = wave * 4 + j;
#pragma unroll
      for (int half = 0; half < 2; half++) {
        unsigned int b = 0;
#pragma unroll
        for (int i = 0; i < 4; i++) {
          b |= (v[j * 4 + half * 2][i] != 0.0f ? 1u : 0u) << i;
          b |= (v[j * 4 + half * 2 + 1][i] != 0.0f ? 1u : 0u) << (4 + i);
        }
        const int o = half * 64 + lane;  // octet index 0..127
        lmaskB[(o >> 3) * kMP + rl * 8 + (o & 7)] = (unsigned char)b;
      }
    }
  }

  // ---- E-tables ----
#pragma unroll
  for (int j = 0; j < 2; j++) {
    const int idx = t + j * 512;  // 0..1023 f32x4 slots
    const int hh = idx >> 8, c4 = (idx & 255) * 4;
    const f32x4 sd = *reinterpret_cast<const f32x4*>(s_dst + hh * kN + colbase + c4);
    f32x4 e1, e2;
#pragma unroll
    for (int i = 0; i < 4; i++) {
      const float u = sd[i] * kLog2e;
      e1[i] = __builtin_amdgcn_exp2f(u);
      e2[i] = __builtin_amdgcn_exp2f(0.2f * u);
    }
    *reinterpret_cast<f32x4*>(&el1[hh][c4]) = e1;
    *reinterpret_cast<f32x4*>(&el2[hh][c4]) = e2;
  }

  // ---- M = exact global max of s_dst[h] via pmax[64 blocks] + shfl ----
  float M = pmax[(lane << 2) | h];
#pragma unroll
  for (int off = 1; off < 64; off <<= 1) M = fmaxf(M, __shfl_xor(M, off));

  float K1[2], K2[2];
#pragma unroll
  for (int rt = 0; rt < 2; rt++) {
    const float A = s_src[h * kN + row0 + rt * 16 + lr];
    const float xb = A + M;
    const float B = fmaxf(xb, 0.2f * xb);
    K1[rt] = __builtin_amdgcn_exp2f((A - B) * kLog2e);
    K2[rt] = __builtin_amdgcn_exp2f((0.2f * A - B) * kLog2e);
  }

  __syncthreads();

  // ---- mask preload: 16 bytes per row-tile per lane ----
  const int Boff = (q << 2) | lg;
  unsigned int cw0[4], cw1[4];
#pragma unroll
  for (int w = 0; w < 4; w++) {
    unsigned int a0 = 0, a1 = 0;
#pragma unroll
    for (int d = 0; d < 4; d++) {
      const int c = w * 4 + d;
      a0 |= (unsigned int)lmaskB[c * kMP + lr * 8 + Boff] << (8 * d);
      a1 |= (unsigned int)lmaskB[c * kMP + (lr + 16) * 8 + Boff] << (8 * d);
    }
    cw0[w] = a0; cw1[w] = a1;
  }

  f32x4 acc0[4] = {}, acc1[4] = {};
  f32x4 accz0 = {}, accz1 = {};
  bf16x8 ones;
#pragma unroll
  for (int e = 0; e < 8; e++) ones[e] = (__bf16)1.0f;

  const float* e1p = &el1[h][q * 32 + 8 * lg];
  const float* e2p = &el2[h][q * 32 + 8 * lg];
  const short8* wb = reinterpret_cast<const short8*>(whb) + (size_t)h * 32768 + lane;
  const int mstep0 = cs * 32 + q;

  // 2-deep B-frag prefetch (overflow prefetches land in-ws, never consumed)
  short8 bw[2][4];
#pragma unroll
  for (int sx = 0; sx < 2; sx++) {
    const short8* p = wb + (size_t)(mstep0 + sx * 2) * 256;
    bw[sx][0] = p[0]; bw[sx][1] = p[64]; bw[sx][2] = p[128]; bw[sx][3] = p[192];
  }

  // 1-unit-ahead E-register prefetch
  f32x4 cE1a = *reinterpret_cast<const f32x4*>(e1p);
  f32x4 cE1b = *reinterpret_cast<const f32x4*>(e1p + 4);
  f32x4 cE2a = *reinterpret_cast<const f32x4*>(e2p);
  f32x4 cE2b = *reinterpret_cast<const f32x4*>(e2p + 4);

#pragma unroll
  for (int it = 0; it < 16; ++it) {
    // issue next unit's E loads FIRST (latency hides under make_p2 + MFMA)
    const int nx = ((it + 1) & 15) * 64;
    const f32x4 nE1a = *reinterpret_cast<const f32x4*>(e1p + nx);
    const f32x4 nE1b = *reinterpret_cast<const f32x4*>(e1p + nx + 4);
    const f32x4 nE2a = *reinterpret_cast<const f32x4*>(e2p + nx);
    const f32x4 nE2b = *reinterpret_cast<const f32x4*>(e2p + nx + 4);

    const short8 cb0 = bw[it & 1][0], cb1 = bw[it & 1][1],
                 cb2 = bw[it & 1][2], cb3 = bw[it & 1][3];
    const short8* pp = wb + (size_t)(mstep0 + (it + 2) * 2) * 256;
    bw[it & 1][0] = pp[0];
    bw[it & 1][1] = pp[64];
    bw[it & 1][2] = pp[128];
    bw[it & 1][3] = pp[192];

    const unsigned cm0 = (cw0[it >> 2] >> ((it & 3) * 8)) & 0xFFu;
    const unsigned cm1 = (cw1[it >> 2] >> ((it & 3) * 8)) & 0xFFu;
    const bf16x8 P0 = make_p2(cE1a, cE1b, cE2a, cE2b, K1[0], K2[0], cm0);
    const bf16x8 P1 = make_p2(cE1a, cE1b, cE2a, cE2b, K1[1], K2[1], cm1);
    const bf16x8 B0 = __builtin_bit_cast(bf16x8, cb0);
    const bf16x8 B1 = __builtin_bit_cast(bf16x8, cb1);
    const bf16x8 B2 = __builtin_bit_cast(bf16x8, cb2);
    const bf16x8 B3 = __builtin_bit_cast(bf16x8, cb3);

    acc0[0] = __builtin_amdgcn_mfma_f32_16x16x32_bf16(P0, B0, acc0[0], 0, 0, 0);
    acc1[0] = __builtin_amdgcn_mfma_f32_16x16x32_bf16(P1, B0, acc1[0], 0, 0, 0);
    acc0[1] = __builtin_amdgcn_mfma_f32_16x16x32_bf16(P0, B1, acc0[1], 0, 0, 0);
    acc1[1] = __builtin_amdgcn_mfma_f32_16x16x32_bf16(P1, B1, acc1[1], 0, 0, 0);
    acc0[2] = __builtin_amdgcn_mfma_f32_16x16x32_bf16(P0, B2, acc0[2], 0, 0, 0);
    acc1[2] = __builtin_amdgcn_mfma_f32_16x16x32_bf16(P1, B2, acc1[2], 0, 0, 0);
    acc0[3] = __builtin_amdgcn_mfma_f32_16x16x32_bf16(P0, B3, acc0[3], 0, 0, 0);
    acc1[3] = __builtin_amdgcn_mfma_f32_16x16x32_bf16(P1, B3, acc1[3], 0, 0, 0);
    accz0 = __builtin_amdgcn_mfma_f32_16x16x32_bf16(P0, ones, accz0, 0, 0, 0);
    accz1 = __builtin_amdgcn_mfma_f32_16x16x32_bf16(P1, ones, accz1, 0, 0, 0);

    cE1a = nE1a; cE1b = nE1b; cE2a = nE2a; cE2b = nE2b;
  }

  // ---- q-combine via LDS (el1/el2 dead now), then single plain store ----
  __syncthreads();
  if (q == 1) {
#pragma unroll
    for (int dt = 0; dt < 4; dt++) {
      *reinterpret_cast<f32x4*>(&el1[h][(dt * 64 + lane) * 4]) = acc0[dt];
      *reinterpret_cast<f32x4*>(&el2[h][(dt * 64 + lane) * 4]) = acc1[dt];
    }
    if (lr == 0) {
#pragma unroll
      for (int r = 0; r < 4; r++) {
        zx[h][lg * 4 + r] = accz0[r];
        zx[h][16 + lg * 4 + r] = accz1[r];
      }
    }
  }
  __syncthreads();
  if (q == 0) {
#pragma unroll
    for (int dt = 0; dt < 4; dt++) {
      acc0[dt] += *reinterpret_cast<const f32x4*>(&el1[h][(dt * 64 + lane) * 4]);
      acc1[dt] += *reinterpret_cast<const f32x4*>(&el2[h][(dt * 64 + lane) * 4]);
    }
    const size_t ob = ((size_t)(cs * 4 + h) * kN + row0) * kD;
#pragma unroll
    for (int dt = 0; dt < 4; dt++)
#pragma unroll
      for (int r = 0; r < 4; r++) {
        accP[ob + (size_t)(lg * 4 + r) * kD + dt * 16 + lr] = acc0[dt][r];
        accP[ob + (size_t)(16 + lg * 4 + r) * kD + dt * 16 + lr] = acc1[dt][r];
      }
    if (lr == 0) {
      const size_t zb = (size_t)(cs * 4 + h) * kN + row0;
#pragma unroll
      for (int r = 0; r < 4; r++) {
        zP[zb + lg * 4 + r] = accz0[r] + zx[h][lg * 4 + r];
        zP[zb + 16 + lg * 4 + r] = accz1[r] + zx[h][16 + lg * 4 + r];
      }
    }
  }
}

// ---------------------------------------------------------------------------
// k_fin: out[n][h*64+d] = elu( sum_cs acc / sum_cs z )
// ---------------------------------------------------------------------------
__global__ __launch_bounds__(256) void k_fin(const float* __restrict__ accP,
                                             const float* __restrict__ zP,
                                             float* __restrict__ out) {
  const int idx = blockIdx.x * 256 + threadIdx.x;  // 262144 float4s
  const int d4 = idx & 15;
  const int hh = (idx >> 4) & 3;
  const int n = idx >> 6;
  f32x4 v = {};
  float z = 0.0f;
#pragma unroll
  for (int s = 0; s < 4; s++) {
    v += reinterpret_cast<const f32x4*>(accP)[((size_t)(s * 4 + hh) * kN + n) * 16 + d4];
    z += zP[(size_t)(s * 4 + hh) * kN + n];
  }
  const float rz = 1.0f / z;
  f32x4 o;
#pragma unroll
  for (int j = 0; j < 4; j++) {
    const float x = v[j] * rz;
    o[j] = x > 0.0f ? x : (__builtin_amdgcn_exp2f(x * kLog2e) - 1.0f);
  }
  reinterpret_cast<f32x4*>(out)[(size_t)n * 64 + hh * 16 + d4] = o;
}

extern "C" void kernel_launch(void* const* d_in, const int* in_sizes, int n_in,
                              void* d_out, int out_size, void* d_ws, size_t ws_size,
                              hipStream_t stream) {
  const float* hmat  = (const float*)d_in[0];
  const float* adj   = (const float*)d_in[1];
  const float* W     = (const float*)d_in[2];
  const float* a_src = (const float*)d_in[3];
  const float* a_dst = (const float*)d_in[4];
  float* out = (float*)d_out;

  char* ws = (char*)d_ws;
  unsigned short* whb = (unsigned short*)(ws);       // 2 MB    @0
  float* s_src  = (float*)(ws + 0x200000);           // 64 KB
  float* s_dst  = (float*)(ws + 0x210000);           // 64 KB
  float* pmax   = (float*)(ws + 0x220000);           // 1 KB
  float* accP   = (float*)(ws + 0x240000);           // 16 MB (4 col-splits)
  float* zP     = (float*)(ws + 0x1240000);          // 256 KB

  hipLaunchKernelGGL(k_wh, dim3(256), dim3(256), 0, stream,
                     hmat, W, a_src, a_dst, whb, s_src, s_dst, pmax);
  hipLaunchKernelGGL(k_attn, dim3(512), dim3(512), 0, stream,
                     adj, whb, s_src, s_dst, pmax, accP, zP);
  hipLaunchKernelGGL(k_fin, dim3(1024), dim3(256), 0, stream, accP, zP, out);
}